// Round 5
// baseline (24.628 us; speedup 1.0000x reference)
//
#include <hip/hip_runtime.h>
#include <hip/hip_fp16.h>

#define NUM_CAMS 6
#define C_FEAT   64
#define HF       16
#define WF       44
#define NPTS     (128*128*8)   // 131072
#define FEAT_ELEMS (NUM_CAMS*C_FEAT*HF*WF)  // 270336
#define PPB      64            // points per block
#define NTHREADS 512

// ---- kernel 1: coalesced transpose (N,C,H,W)->(N,H,W,C) fp16, + proj matmul ----
// blocks 0..95: one (n,y) plane each (64c x 44x). block 96: proj = cam2img@ego2cam.
__global__ __launch_bounds__(256) void uvt_prep(const float* __restrict__ in,
                                                const float* __restrict__ ego2cam,
                                                const float* __restrict__ cam2img,
                                                __half* __restrict__ featsT,
                                                float* __restrict__ projws) {
    const int blk = blockIdx.x;
    if (blk < NUM_CAMS * HF) {
        __shared__ float s[WF][C_FEAT + 1];
        const int n = blk / HF, y = blk % HF;
        const float* src = in + n * C_FEAT * HF * WF + y * WF;
        for (int e = threadIdx.x; e < C_FEAT * WF; e += 256) {
            const int c = e / WF, x = e - c * WF;     // x-contiguous reads
            s[x][c] = src[c * HF * WF + x];
        }
        __syncthreads();
        __half* dst = featsT + (n * HF + y) * WF * C_FEAT;
        for (int e = threadIdx.x; e < C_FEAT * WF; e += 256) {
            const int x = e >> 6, c = e & 63;         // contiguous writes
            dst[e] = __float2half(s[x][c]);
        }
    } else {
        const int t = threadIdx.x;
        if (t < NUM_CAMS * 12) {
            const int cam = t / 12, e = t - cam * 12;
            const int i = e >> 2, j = e & 3;
            const float* A = cam2img + cam * 16;
            const float* B = ego2cam + cam * 16;
            float sum = 0.f;
            #pragma unroll
            for (int k = 0; k < 4; ++k) sum += A[i*4 + k] * B[k*4 + j];
            projws[cam * 12 + e] = sum;
        }
    }
}

// per (point,cam) sampling params
struct alignas(32) PC {
    __half2 w00, w10, w01, w11;   // duplicated weights; zeroed for OOB/invalid
    int base, dx, dy, valid;      // half-element offsets; dx=0|64, dy=0|WF*64
};

// ---- kernel 2: project + packed-half bilinear + fuse, direct stores ----
// 512 threads = 64 points x 8 channel-octs; oct = tid&7 (8 ch = 16B), pl = tid>>3
// wave = 8 octs x 8 points -> each gather instr: 8 x 128B contiguous segments
__global__ __launch_bounds__(NTHREADS) void uvt_fuse(
    const __half* __restrict__ featsT,  // (6,16,44,64) fp16
    const float* __restrict__ projws,   // (6,3,4)
    const float* __restrict__ vox,      // (3, NPTS)
    float* __restrict__ out)            // (64, NPTS)
{
    __shared__ PC s_pc[NUM_CAMS][PPB];

    const int tid = threadIdx.x;
    const int p0  = blockIdx.x * PPB;

    // ---- phase 1: per (point,cam) params; cam is wave-uniform -> scalar proj ----
    if (tid < NUM_CAMS * PPB) {         // 384 threads, 6 waves
        const int cam = __builtin_amdgcn_readfirstlane(tid >> 6);
        const int lp  = tid & 63;
        const int p   = p0 + lp;
        const float* M = projws + cam * 12;

        const float px = vox[p];
        const float py = vox[NPTS + p];
        const float pz = vox[2 * NPTS + p];
        const float ud = M[0]*px + M[1]*py + M[2]*pz  + M[3];
        const float vd = M[4]*px + M[5]*py + M[6]*pz  + M[7];
        const float d  = M[8]*px + M[9]*py + M[10]*pz + M[11];
        const float id = 1.0f / (d + 1e-6f);
        const float u  = ud * id;
        const float v  = vd * id;
        const bool valid = (d > 0.1f) && (u >= 0.f) && (u <= 703.f)
                                      && (v >= 0.f) && (v <= 255.f);
        PC pc;
        if (valid) {
            const float x  = u * 0.0625f;
            const float y  = v * 0.0625f;
            const float xf = floorf(x), yf = floorf(y);
            const int   x0 = (int)xf,   y0 = (int)yf;
            const float wx1 = x - xf,  wy1 = y - yf;
            const float wx0 = 1.f - wx1, wy0 = 1.f - wy1;
            const bool bx = (x0 < WF - 1);
            const bool by = (y0 < HF - 1);
            pc.w00 = __float2half2_rn(wx0 * wy0);
            pc.w10 = __float2half2_rn(bx ? wx1 * wy0 : 0.f);
            pc.w01 = __float2half2_rn(by ? wx0 * wy1 : 0.f);
            pc.w11 = __float2half2_rn((bx && by) ? wx1 * wy1 : 0.f);
            pc.base = ((cam * HF + y0) * WF + x0) << 6;
            pc.dx   = bx ? C_FEAT : 0;
            pc.dy   = by ? WF * C_FEAT : 0;
            pc.valid = 1;
        } else {
            pc.w00 = pc.w10 = pc.w01 = pc.w11 = __float2half2_rn(0.f);
            pc.base = pc.dx = pc.dy = 0;
            pc.valid = 0;
        }
        s_pc[cam][lp] = pc;
    }
    __syncthreads();

    // ---- phase 2: valid mask + gated packed-half gather ----
    const int oct = tid & 7;
    const int pl  = tid >> 3;
    int vm = 0, cnt = 0;
    #pragma unroll
    for (int cam = 0; cam < NUM_CAMS; ++cam) {
        const int v = s_pc[cam][pl].valid;   // 4B broadcast reads
        vm |= v << cam;
        cnt += v;
    }
    const float inv = 1.0f / (float)(cnt > 0 ? cnt : 1);

    float2 a0 = {0.f,0.f}, a1 = {0.f,0.f}, a2 = {0.f,0.f}, a3 = {0.f,0.f};
    #pragma unroll
    for (int cam = 0; cam < NUM_CAMS; ++cam) {
        if ((vm >> cam) & 1) {    // exec-masked; no traffic when invalid
            const PC pc = s_pc[cam][pl];
            const __half* b = featsT + pc.base + (oct << 3);
            const uint4 r00 = *(const uint4*)(b);
            const uint4 r10 = *(const uint4*)(b + pc.dx);
            const uint4 r01 = *(const uint4*)(b + pc.dy);
            const uint4 r11 = *(const uint4*)(b + pc.dx + pc.dy);

            #define BC(u_) __builtin_bit_cast(__half2, u_)
            __half2 s0 = __hmul2(pc.w00, BC(r00.x));
            s0 = __hfma2(pc.w10, BC(r10.x), s0);
            s0 = __hfma2(pc.w01, BC(r01.x), s0);
            s0 = __hfma2(pc.w11, BC(r11.x), s0);
            __half2 s1 = __hmul2(pc.w00, BC(r00.y));
            s1 = __hfma2(pc.w10, BC(r10.y), s1);
            s1 = __hfma2(pc.w01, BC(r01.y), s1);
            s1 = __hfma2(pc.w11, BC(r11.y), s1);
            __half2 s2 = __hmul2(pc.w00, BC(r00.z));
            s2 = __hfma2(pc.w10, BC(r10.z), s2);
            s2 = __hfma2(pc.w01, BC(r01.z), s2);
            s2 = __hfma2(pc.w11, BC(r11.z), s2);
            __half2 s3 = __hmul2(pc.w00, BC(r00.w));
            s3 = __hfma2(pc.w10, BC(r10.w), s3);
            s3 = __hfma2(pc.w01, BC(r01.w), s3);
            s3 = __hfma2(pc.w11, BC(r11.w), s3);
            #undef BC

            const float2 f0 = __half22float2(s0);
            const float2 f1 = __half22float2(s1);
            const float2 f2 = __half22float2(s2);
            const float2 f3 = __half22float2(s3);
            a0.x += f0.x; a0.y += f0.y;
            a1.x += f1.x; a1.y += f1.y;
            a2.x += f2.x; a2.y += f2.y;
            a3.x += f3.x; a3.y += f3.y;
        }
    }

    // ---- phase 3: direct stores (8 x 4B, 32B segments merged in L2) ----
    float* o = out + (oct << 3) * NPTS + p0 + pl;
    o[0 * NPTS] = a0.x * inv;
    o[1 * NPTS] = a0.y * inv;
    o[2 * NPTS] = a1.x * inv;
    o[3 * NPTS] = a1.y * inv;
    o[4 * NPTS] = a2.x * inv;
    o[5 * NPTS] = a2.y * inv;
    o[6 * NPTS] = a3.x * inv;
    o[7 * NPTS] = a3.y * inv;
}

// ---------------------------------------------------------------------------
extern "C" void kernel_launch(void* const* d_in, const int* in_sizes, int n_in,
                              void* d_out, int out_size, void* d_ws, size_t ws_size,
                              hipStream_t stream) {
    const float* img_feats = (const float*)d_in[0];  // (6,64,16,44)
    const float* ego2cam   = (const float*)d_in[1];  // (6,4,4)
    const float* cam2img   = (const float*)d_in[2];  // (6,4,4)
    const float* vox       = (const float*)d_in[3];  // (3,8,128,128)
    float* out = (float*)d_out;                      // (1,64,8,128,128)

    __half* featsT = (__half*)d_ws;                  // 270336 halves
    float*  projws = (float*)((char*)d_ws + FEAT_ELEMS * sizeof(__half)); // 72 floats

    uvt_prep<<<NUM_CAMS * HF + 1, 256, 0, stream>>>(img_feats, ego2cam, cam2img,
                                                    featsT, projws);
    uvt_fuse<<<NPTS / PPB, NTHREADS, 0, stream>>>(featsT, projws, vox, out);
}

// Round 6
// 20.770 us; speedup vs baseline: 1.1857x; 1.1857x over previous
//
#include <hip/hip_runtime.h>
#include <hip/hip_fp16.h>

#define NUM_CAMS 6
#define C_FEAT   64
#define HF       16
#define WF       44
#define NPTS     (128*128*8)   // 131072
#define FEAT_ELEMS (NUM_CAMS*C_FEAT*HF*WF)  // 270336
#define PPB      64            // points per block
#define NTHREADS 512

// ---- kernel 1: coalesced transpose (N,C,H,W)->(N,H,W,C) fp16, + proj matmul ----
__global__ __launch_bounds__(256) void uvt_prep(const float* __restrict__ in,
                                                const float* __restrict__ ego2cam,
                                                const float* __restrict__ cam2img,
                                                __half* __restrict__ featsT,
                                                float* __restrict__ projws) {
    const int blk = blockIdx.x;
    if (blk < NUM_CAMS * HF) {
        __shared__ float s[WF][C_FEAT + 1];
        const int n = blk / HF, y = blk % HF;
        const float* src = in + n * C_FEAT * HF * WF + y * WF;
        for (int e = threadIdx.x; e < C_FEAT * WF; e += 256) {
            const int c = e / WF, x = e - c * WF;     // x-contiguous reads
            s[x][c] = src[c * HF * WF + x];
        }
        __syncthreads();
        __half* dst = featsT + (n * HF + y) * WF * C_FEAT;
        for (int e = threadIdx.x; e < C_FEAT * WF; e += 256) {
            const int x = e >> 6, c = e & 63;         // contiguous writes
            dst[e] = __float2half(s[x][c]);
        }
    } else {
        const int t = threadIdx.x;
        if (t < NUM_CAMS * 12) {
            const int cam = t / 12, e = t - cam * 12;
            const int i = e >> 2, j = e & 3;
            const float* A = cam2img + cam * 16;
            const float* B = ego2cam + cam * 16;
            float sum = 0.f;
            #pragma unroll
            for (int k = 0; k < 4; ++k) sum += A[i*4 + k] * B[k*4 + j];
            projws[cam * 12 + e] = sum;
        }
    }
}

// per (point,cam) sampling params
struct alignas(32) PC {
    __half2 w00, w10, w01, w11;   // duplicated weights; zeroed for OOB/invalid
    int base, dx, dy, valid;      // half-element offsets; dx=0|64, dy=0|WF*64
};

// ---- kernel 2: project + packed-half bilinear + fuse, LDS-coalesced stores ----
// 512 threads = 64 points x 8 channel-octs; oct = tid&7 (16B), pl = tid>>3
__global__ __launch_bounds__(NTHREADS) void uvt_fuse(
    const __half* __restrict__ featsT,  // (6,16,44,64) fp16
    const float* __restrict__ projws,   // (6,3,4)
    const float* __restrict__ vox,      // (3, NPTS)
    float* __restrict__ out)            // (64, NPTS)
{
    __shared__ PC    s_pc[NUM_CAMS][PPB];
    __shared__ float s_out[PPB][C_FEAT + 1];

    const int tid = threadIdx.x;
    const int p0  = blockIdx.x * PPB;

    // ---- phase 1: per (point,cam) params; one cam per wave -> scalar proj ----
    if (tid < NUM_CAMS * PPB) {         // 384 threads, 6 waves
        const int cam = __builtin_amdgcn_readfirstlane(tid >> 6);
        const int lp  = tid & 63;
        const int p   = p0 + lp;
        const float* M = projws + cam * 12;

        const float px = vox[p];
        const float py = vox[NPTS + p];
        const float pz = vox[2 * NPTS + p];
        const float ud = M[0]*px + M[1]*py + M[2]*pz  + M[3];
        const float vd = M[4]*px + M[5]*py + M[6]*pz  + M[7];
        const float d  = M[8]*px + M[9]*py + M[10]*pz + M[11];
        const float id = 1.0f / (d + 1e-6f);
        const float u  = ud * id;
        const float v  = vd * id;
        const bool valid = (d > 0.1f) && (u >= 0.f) && (u <= 703.f)
                                      && (v >= 0.f) && (v <= 255.f);
        PC pc;
        if (valid) {
            const float x  = u * 0.0625f;
            const float y  = v * 0.0625f;
            const float xf = floorf(x), yf = floorf(y);
            const int   x0 = (int)xf,   y0 = (int)yf;
            const float wx1 = x - xf,  wy1 = y - yf;
            const float wx0 = 1.f - wx1, wy0 = 1.f - wy1;
            const bool bx = (x0 < WF - 1);
            const bool by = (y0 < HF - 1);
            pc.w00 = __float2half2_rn(wx0 * wy0);
            pc.w10 = __float2half2_rn(bx ? wx1 * wy0 : 0.f);
            pc.w01 = __float2half2_rn(by ? wx0 * wy1 : 0.f);
            pc.w11 = __float2half2_rn((bx && by) ? wx1 * wy1 : 0.f);
            pc.base = ((cam * HF + y0) * WF + x0) << 6;
            pc.dx   = bx ? C_FEAT : 0;
            pc.dy   = by ? WF * C_FEAT : 0;
            pc.valid = 1;
        } else {
            pc.w00 = pc.w10 = pc.w01 = pc.w11 = __float2half2_rn(0.f);
            pc.base = pc.dx = pc.dy = 0;
            pc.valid = 0;
        }
        s_pc[cam][lp] = pc;
    }
    __syncthreads();

    // ---- phase 2: valid mask + gated packed-half gather ----
    const int oct = tid & 7;
    const int pl  = tid >> 3;
    int vm = 0, cnt = 0;
    #pragma unroll
    for (int cam = 0; cam < NUM_CAMS; ++cam) {
        const int v = s_pc[cam][pl].valid;
        vm |= v << cam;
        cnt += v;
    }
    const float inv = 1.0f / (float)(cnt > 0 ? cnt : 1);

    float2 a0 = {0.f,0.f}, a1 = {0.f,0.f}, a2 = {0.f,0.f}, a3 = {0.f,0.f};
    #pragma unroll
    for (int cam = 0; cam < NUM_CAMS; ++cam) {
        if ((vm >> cam) & 1) {    // exec-masked; no traffic when invalid
            const PC pc = s_pc[cam][pl];
            const __half* b = featsT + pc.base + (oct << 3);
            const uint4 r00 = *(const uint4*)(b);
            const uint4 r10 = *(const uint4*)(b + pc.dx);
            const uint4 r01 = *(const uint4*)(b + pc.dy);
            const uint4 r11 = *(const uint4*)(b + pc.dx + pc.dy);

            #define BC(u_) __builtin_bit_cast(__half2, u_)
            __half2 s0 = __hmul2(pc.w00, BC(r00.x));
            s0 = __hfma2(pc.w10, BC(r10.x), s0);
            s0 = __hfma2(pc.w01, BC(r01.x), s0);
            s0 = __hfma2(pc.w11, BC(r11.x), s0);
            __half2 s1 = __hmul2(pc.w00, BC(r00.y));
            s1 = __hfma2(pc.w10, BC(r10.y), s1);
            s1 = __hfma2(pc.w01, BC(r01.y), s1);
            s1 = __hfma2(pc.w11, BC(r11.y), s1);
            __half2 s2 = __hmul2(pc.w00, BC(r00.z));
            s2 = __hfma2(pc.w10, BC(r10.z), s2);
            s2 = __hfma2(pc.w01, BC(r01.z), s2);
            s2 = __hfma2(pc.w11, BC(r11.z), s2);
            __half2 s3 = __hmul2(pc.w00, BC(r00.w));
            s3 = __hfma2(pc.w10, BC(r10.w), s3);
            s3 = __hfma2(pc.w01, BC(r01.w), s3);
            s3 = __hfma2(pc.w11, BC(r11.w), s3);
            #undef BC

            const float2 f0 = __half22float2(s0);
            const float2 f1 = __half22float2(s1);
            const float2 f2 = __half22float2(s2);
            const float2 f3 = __half22float2(s3);
            a0.x += f0.x; a0.y += f0.y;
            a1.x += f1.x; a1.y += f1.y;
            a2.x += f2.x; a2.y += f2.y;
            a3.x += f3.x; a3.y += f3.y;
        }
    }

    // ---- phase 3: transpose through LDS, 256B-coalesced stores ----
    const int cb = oct << 3;
    s_out[pl][cb + 0] = a0.x * inv;
    s_out[pl][cb + 1] = a0.y * inv;
    s_out[pl][cb + 2] = a1.x * inv;
    s_out[pl][cb + 3] = a1.y * inv;
    s_out[pl][cb + 4] = a2.x * inv;
    s_out[pl][cb + 5] = a2.y * inv;
    s_out[pl][cb + 6] = a3.x * inv;
    s_out[pl][cb + 7] = a3.y * inv;
    __syncthreads();

    #pragma unroll
    for (int i = 0; i < 8; ++i) {
        const int idx = tid + NTHREADS * i;   // 0..4095
        const int c   = idx >> 6;             // channel
        const int lp  = idx & 63;             // point (64 consecutive per wave)
        out[c * NPTS + p0 + lp] = s_out[lp][c];
    }
}

// ---------------------------------------------------------------------------
extern "C" void kernel_launch(void* const* d_in, const int* in_sizes, int n_in,
                              void* d_out, int out_size, void* d_ws, size_t ws_size,
                              hipStream_t stream) {
    const float* img_feats = (const float*)d_in[0];  // (6,64,16,44)
    const float* ego2cam   = (const float*)d_in[1];  // (6,4,4)
    const float* cam2img   = (const float*)d_in[2];  // (6,4,4)
    const float* vox       = (const float*)d_in[3];  // (3,8,128,128)
    float* out = (float*)d_out;                      // (1,64,8,128,128)

    __half* featsT = (__half*)d_ws;                  // 270336 halves
    float*  projws = (float*)((char*)d_ws + FEAT_ELEMS * sizeof(__half)); // 72 floats

    uvt_prep<<<NUM_CAMS * HF + 1, 256, 0, stream>>>(img_feats, ego2cam, cam2img,
                                                    featsT, projws);
    uvt_fuse<<<NPTS / PPB, NTHREADS, 0, stream>>>(featsT, projws, vox, out);
}